// Round 16
// baseline (272.613 us; speedup 1.0000x reference)
//
#include <hip/hip_runtime.h>
#include <hip/hip_bf16.h>
#include <cstdint>
#include <cstddef>

#define B_ 2
#define N_ 2048
#define C_ 384
#define K_ 20
#define EPS_ 1e-5f
#define SLOPE_ 0.2f

typedef __attribute__((ext_vector_type(8))) short short8;
typedef __attribute__((ext_vector_type(4))) short short4v;
typedef __attribute__((ext_vector_type(4))) float floatx4;

#define MFMA(a, b, c) __builtin_amdgcn_mfma_f32_16x16x32_bf16((a), (b), (c), 0, 0, 0)

// ---------------- helpers ----------------
__device__ __forceinline__ unsigned fmap(float f) {
  unsigned u = __float_as_uint(f);
  return (u & 0x80000000u) ? ~u : (u | 0x80000000u);
}
__device__ __forceinline__ float funmap(unsigned u) {
  unsigned bits = (u & 0x80000000u) ? (u ^ 0x80000000u) : ~u;
  return __uint_as_float(bits);
}
__device__ __forceinline__ short f2b(float f) {  // RNE fp32->bf16 bits
  __hip_bfloat16 h = __float2bfloat16(f);
  unsigned short u;
  __builtin_memcpy(&u, &h, 2);
  return (short)u;
}
__device__ __forceinline__ float b2f(short s) {
  unsigned u = ((unsigned)(unsigned short)s) << 16;
  return __uint_as_float(u);
}

// stage one 16x32 bf16 subtile in MFMA-fragment order (dest linear, src permuted)
__device__ __forceinline__ void stage16(const short* g, int ld, short* dst, int lane) {
  const short* src = g + (size_t)(lane & 15) * ld + ((lane >> 4) << 3);
  __builtin_amdgcn_global_load_lds(
      (const __attribute__((address_space(1))) void*)src,
      (__attribute__((address_space(3))) void*)dst, 16, 0, 0);
}

// ---- 128x128-tile, K=384, BK=32 split-bf16 GEMM core (m97 structure) ----
__device__ __forceinline__ void gemm128(const short* AH, const short* AL, int ldA,
                                        const short* BH, const short* BL, int ldB,
                                        short (*sst)[4096], int tid,
                                        floatx4 acc[4][4]) {
  int lane = tid & 63, w = tid >> 6;
  int wr = w >> 1, wc = w & 1;
  for (int kc = 0; kc < C_; kc += 32) {
    __syncthreads();
#pragma unroll
    for (int ss = 0; ss < 2; ss++) {
      int s = w * 2 + ss;  // subtile 0..7, rows s*16
      int ro = s * 16;
      stage16(AH + (size_t)ro * ldA + kc, ldA, &sst[0][s * 512], lane);
      stage16(AL + (size_t)ro * ldA + kc, ldA, &sst[1][s * 512], lane);
      stage16(BH + (size_t)ro * ldB + kc, ldB, &sst[2][s * 512], lane);
      stage16(BL + (size_t)ro * ldB + kc, ldB, &sst[3][s * 512], lane);
    }
    __syncthreads();
    short8 ah[4], al[4], bh[4], bl[4];
#pragma unroll
    for (int m = 0; m < 4; m++) {
      ah[m] = *(const short8*)&sst[0][(wr * 4 + m) * 512 + lane * 8];
      al[m] = *(const short8*)&sst[1][(wr * 4 + m) * 512 + lane * 8];
      bh[m] = *(const short8*)&sst[2][(wc * 4 + m) * 512 + lane * 8];
      bl[m] = *(const short8*)&sst[3][(wc * 4 + m) * 512 + lane * 8];
    }
#pragma unroll
    for (int m = 0; m < 4; m++)
#pragma unroll
      for (int n = 0; n < 4; n++) {
        acc[m][n] = MFMA(ah[m], bh[n], acc[m][n]);
        acc[m][n] = MFMA(ah[m], bl[n], acc[m][n]);
        acc[m][n] = MFMA(al[m], bh[n], acc[m][n]);
      }
  }
}

// ---- fused startup: 3x prepw (x4 vec), prepwp (x4 vec), stage-init, transpose ----
__global__ __launch_bounds__(256) void k_prep(
    const float* __restrict__ x,
    const float* __restrict__ We0, const float* __restrict__ g0, const float* __restrict__ b0,
    const float* __restrict__ m0, const float* __restrict__ v0,
    const float* __restrict__ We1, const float* __restrict__ g1, const float* __restrict__ b1,
    const float* __restrict__ m1, const float* __restrict__ v1,
    const float* __restrict__ We2, const float* __restrict__ g2, const float* __restrict__ b2,
    const float* __restrict__ m2, const float* __restrict__ v2,
    const float* __restrict__ Wp, const float* __restrict__ gp, const float* __restrict__ bp,
    const float* __restrict__ mp, const float* __restrict__ vp,
    short* __restrict__ H0, short* __restrict__ L0,
    short* __restrict__ WbfH, short* __restrict__ WbfL,
    short* __restrict__ WpH, short* __restrict__ WpL,
    float* __restrict__ bz, float* __restrict__ bz2,
    unsigned* __restrict__ stage) {
  __shared__ float tile[32][33];
  int bx = blockIdx.x;
  if (bx < 864) {  // edge weight prep, layer l, 4 elems/thread
    int l = bx / 288;
    int t4 = (bx % 288) * 256 + threadIdx.x;  // 73728 per layer (exact)
    const float* We = (l == 0) ? We0 : (l == 1) ? We1 : We2;
    const float* g  = (l == 0) ? g0  : (l == 1) ? g1  : g2;
    const float* bb = (l == 0) ? b0  : (l == 1) ? b1  : b2;
    const float* m  = (l == 0) ? m0  : (l == 1) ? m1  : m2;
    const float* v  = (l == 0) ? v0  : (l == 1) ? v1  : v2;
    short* WH = WbfH + (size_t)l * 2 * C_ * C_;
    short* WL = WbfL + (size_t)l * 2 * C_ * C_;
    float* bzl = bz + (size_t)l * 2 * C_;
    int o2 = t4 / (C_ / 4), c = (t4 % (C_ / 4)) * 4;
    int o = (o2 < C_) ? o2 : (o2 - C_);
    float sc = g[o] * rsqrtf(v[o] + EPS_);
    float4 wa = *(const float4*)(We + (size_t)o * 2 * C_ + c);
    float wv[4];
    if (o2 < C_) {
      wv[0] = sc * wa.x; wv[1] = sc * wa.y; wv[2] = sc * wa.z; wv[3] = sc * wa.w;
    } else {
      float4 wb = *(const float4*)(We + (size_t)o * 2 * C_ + C_ + c);
      wv[0] = sc * (wb.x - wa.x); wv[1] = sc * (wb.y - wa.y);
      wv[2] = sc * (wb.z - wa.z); wv[3] = sc * (wb.w - wa.w);
    }
    short4v hs, ls;
#pragma unroll
    for (int j = 0; j < 4; j++) {
      short hb = f2b(wv[j]);
      hs[j] = hb;
      ls[j] = f2b(wv[j] - b2f(hb));
    }
    *(short4v*)(WH + (size_t)t4 * 4) = hs;
    *(short4v*)(WL + (size_t)t4 * 4) = ls;
    if (t4 < 2 * C_ / 4) {
#pragma unroll
      for (int jj = 0; jj < 4; jj++) {
        int tt = t4 * 4 + jj;
        bzl[tt] = (tt < C_) ? 0.f
                            : (bb[tt - C_] - m[tt - C_] * (g[tt - C_] * rsqrtf(v[tt - C_] + EPS_)));
      }
    }
  } else if (bx < 1296) {  // final weight prep, 4 elems/thread
    int t4 = (bx - 864) * 256 + threadIdx.x;  // 110592 (exact)
    int o = t4 / (3 * C_ / 4);
    float sc = gp[o] * rsqrtf(vp[o] + EPS_);
    float4 wa = *(const float4*)(Wp + (size_t)t4 * 4);
    float wv[4] = {sc * wa.x, sc * wa.y, sc * wa.z, sc * wa.w};
    short4v hs, ls;
#pragma unroll
    for (int j = 0; j < 4; j++) {
      short hb = f2b(wv[j]);
      hs[j] = hb;
      ls[j] = f2b(wv[j] - b2f(hb));
    }
    *(short4v*)(WpH + (size_t)t4 * 4) = hs;
    *(short4v*)(WpL + (size_t)t4 * 4) = ls;
    if (t4 < C_ / 4) {
#pragma unroll
      for (int jj = 0; jj < 4; jj++) {
        int tt = t4 * 4 + jj;
        float s2 = gp[tt] * rsqrtf(vp[tt] + EPS_);
        bz2[tt] = bp[tt] - mp[tt] * s2;
      }
    }
  } else if (bx < 1299) {  // stage init
    int t = (bx - 1296) * 256 + threadIdx.x;
    if (t < B_ * C_) stage[t] = 0x007FFFFFu;  // fmap(-inf)
  } else {  // transpose x -> H0/L0
    int i = bx - 1299;
    int bn = i % 64, bc = (i / 64) % 12, b = i / 768;
    int tx = threadIdx.x & 31, ty = threadIdx.x >> 5;
    const float* src = x + ((size_t)b * C_ + bc * 32) * N_ + bn * 32;
#pragma unroll
    for (int j = 0; j < 32; j += 8)
      tile[ty + j][tx] = src[(size_t)(ty + j) * N_ + tx];
    __syncthreads();
#pragma unroll
    for (int j = 0; j < 32; j += 8) {
      float val = tile[tx][ty + j];
      short hb = f2b(val);
      short lb = f2b(val - b2f(hb));
      size_t off = ((size_t)b * N_ + bn * 32 + ty + j) * C_ + bc * 32 + tx;
      H0[off] = hb;
      L0[off] = lb;
    }
  }
}

// ---- row squared norms (layer 0 only) ----
__global__ __launch_bounds__(256) void k_rowsq(const short* __restrict__ H,
                                               const short* __restrict__ L,
                                               float* __restrict__ sq) {
  int row  = blockIdx.x * 4 + (threadIdx.x >> 6);
  int lane = threadIdx.x & 63;
  const short* ph = H + (size_t)row * C_;
  const short* pl = L + (size_t)row * C_;
  float v = 0.f;
  if (lane < C_ / 8) {
    short8 h8 = *(const short8*)(ph + lane * 8);
    short8 l8 = *(const short8*)(pl + lane * 8);
#pragma unroll
    for (int j = 0; j < 8; j++) {
      float t = b2f(h8[j]) + b2f(l8[j]);
      v += t * t;
    }
  }
#pragma unroll
  for (int off = 32; off; off >>= 1) v += __shfl_xor(v, off, 64);
  if (lane == 0) sq[row] = v;
}

// ---- mega kernel: gram (128x128 triangular, reg-mirror) || yz GEMM ----
__global__ __launch_bounds__(256) void k_gramyz(const short* __restrict__ H,
                                                const short* __restrict__ L,
                                                int ldh, int coff,
                                                const float* __restrict__ sq,
                                                float* __restrict__ Gm,
                                                const short* __restrict__ WH,
                                                const short* __restrict__ WL,
                                                const float* __restrict__ bz,
                                                float* __restrict__ YZ) {
  __shared__ __align__(16) short sst[4][4096];
  int bx = blockIdx.x;
  int tid = threadIdx.x, lane = tid & 63, w = tid >> 6;
  int wr = w >> 1, wc = w & 1;
  int fr = lane & 15, r0 = (lane >> 4) << 2;
  floatx4 acc[4][4] = {};

  if (bx < 136 * B_) {
    // ---------- gram path: 128x128 tiles, upper triangle ----------
    int b = bx / 136, t = bx % 136;
    int p = (int)((sqrtf(8.f * t + 1.f) - 1.f) * 0.5f);
    while ((p + 1) * (p + 2) / 2 <= t) p++;
    while (p * (p + 1) / 2 > t) p--;
    int q = t - p * (p + 1) / 2;
    int bi = q, bj = p;  // bi <= bj

    const short* Hb = H + (size_t)b * N_ * ldh + coff;
    const short* Lb = L + (size_t)b * N_ * ldh + coff;
    gemm128(Hb + (size_t)(bi * 128) * ldh, Lb + (size_t)(bi * 128) * ldh, ldh,
            Hb + (size_t)(bj * 128) * ldh, Lb + (size_t)(bj * 128) * ldh, ldh,
            sst, tid, acc);

    const float* sqb = sq + (size_t)b * N_;
    float* gbase = Gm + (size_t)b * N_ * N_;
    int rbase = bi * 128 + wr * 64;
    int cbase = bj * 128 + wc * 64;
#pragma unroll
    for (int n = 0; n < 4; n++) {
      int col = cbase + n * 16 + fr;
      float sqB = sqb[col];
#pragma unroll
      for (int m = 0; m < 4; m++)
#pragma unroll
        for (int i = 0; i < 4; i++)
          gbase[(size_t)(rbase + m * 16 + r0 + i) * N_ + col] = 2.f * acc[m][n][i] - sqB;
    }
    if (bi != bj) {
#pragma unroll
      for (int m = 0; m < 4; m++) {
        int mc0 = rbase + m * 16 + r0;
        float4 sqA = *(const float4*)(sqb + mc0);
        float sqs[4] = {sqA.x, sqA.y, sqA.z, sqA.w};
#pragma unroll
        for (int n = 0; n < 4; n++) {
          int mrow = cbase + n * 16 + fr;
          float4 mv = make_float4(2.f * acc[m][n][0] - sqs[0], 2.f * acc[m][n][1] - sqs[1],
                                  2.f * acc[m][n][2] - sqs[2], 2.f * acc[m][n][3] - sqs[3]);
          *(float4*)(gbase + (size_t)mrow * N_ + mc0) = mv;
        }
      }
    }
  } else {
    // ---------- yz path: 128x128 tiles ----------
    int i = bx - 136 * B_;
    int bi = i & 15, bj = (i >> 4) % 6, b = i / (16 * 6);
    const short* Hb = H + (size_t)b * N_ * ldh + coff;
    const short* Lb = L + (size_t)b * N_ * ldh + coff;
    gemm128(Hb + (size_t)(bi * 128) * ldh, Lb + (size_t)(bi * 128) * ldh, ldh,
            WH + (size_t)(bj * 128) * C_, WL + (size_t)(bj * 128) * C_, C_,
            sst, tid, acc);
    int rbase = bi * 128 + wr * 64;
    int cbase = bj * 128 + wc * 64;
#pragma unroll
    for (int n = 0; n < 4; n++) {
      int gcol = cbase + n * 16 + fr;
      float bzv = bz[gcol];
#pragma unroll
      for (int m = 0; m < 4; m++)
#pragma unroll
        for (int i2 = 0; i2 < 4; i2++)
          YZ[((size_t)b * N_ + rbase + m * 16 + r0 + i2) * (2 * C_) + gcol] =
              acc[m][n][i2] + bzv;
    }
  }
}

// ---- top-K primitives: per-lane sorted top-4 cache + lazy refill ----
__device__ __forceinline__ void tk_insert(float v, int j, bool valid,
                                          float& t0, float& t1, float& t2, float& t3,
                                          int& j0, int& j1, int& j2, int& j3) {
  bool c0 = valid && (v > t0);
  bool c1 = valid && (v > t1);
  bool c2 = valid && (v > t2);
  bool c3 = valid && (v > t3);
  t3 = c2 ? t2 : (c3 ? v : t3);  j3 = c2 ? j2 : (c3 ? j : j3);
  t2 = c1 ? t1 : (c2 ? v : t2);  j2 = c1 ? j1 : (c2 ? j : j2);
  t1 = c0 ? t0 : (c1 ? v : t1);  j1 = c0 ? j0 : (c1 ? j : j1);
  t0 = c0 ? v : t0;              j0 = c0 ? j : j0;
}

__device__ __forceinline__ void tk_refill(const float* va, int lane,
                                          float lastV, int lastJ,
                                          float& t0, float& t1, float& t2, float& t3,
                                          int& j0, int& j1, int& j2, int& j3) {
  t0 = t1 = t2 = t3 = -INFINITY;
  j0 = j1 = j2 = j3 = 0x7FFFFFFF;
#pragma unroll
  for (int s = 0; s < 32; s++) {
    int j = (s >> 2) * 256 + lane * 4 + (s & 3);
    float v = va[s];
    // strictly after (lastV, lastJ) in (v desc, j asc) order
    bool valid = (v < lastV) || (v == lastV && j > lastJ);
    tk_insert(v, j, valid, t0, t1, t2, t3, j0, j1, j2, j3);
  }
}

// ---- top-K: wave processes TWO rows (ILP overlaps the dependent shfl chains) ----
__global__ __launch_bounds__(256) void k_topk(const float* __restrict__ Gm,
                                              int* __restrict__ idx) {
  int lane = threadIdx.x & 63, wv = threadIdx.x >> 6;
  int b = blockIdx.y;
  int nA = blockIdx.x * 8 + wv * 2;
  int nB = nA + 1;
  const float4* growA = (const float4*)(Gm + ((size_t)b * N_ + nA) * N_);
  const float4* growB = (const float4*)(Gm + ((size_t)b * N_ + nB) * N_);
  float vaA[32], vaB[32];
#pragma unroll
  for (int q = 0; q < 8; q++) {
    float4 a4 = growA[q * 64 + lane];
    float4 b4 = growB[q * 64 + lane];
    vaA[q * 4 + 0] = a4.x; vaA[q * 4 + 1] = a4.y;
    vaA[q * 4 + 2] = a4.z; vaA[q * 4 + 3] = a4.w;
    vaB[q * 4 + 0] = b4.x; vaB[q * 4 + 1] = b4.y;
    vaB[q * 4 + 2] = b4.z; vaB[q * 4 + 3] = b4.w;
  }
  float tA0, tA1, tA2, tA3, tB0, tB1, tB2, tB3;
  int jA0, jA1, jA2, jA3, jB0, jB1, jB2, jB3;
  tk_refill(vaA, lane, INFINITY, -1, tA0, tA1, tA2, tA3, jA0, jA1, jA2, jA3);
  tk_refill(vaB, lane, INFINITY, -1, tB0, tB1, tB2, tB3, jB0, jB1, jB2, jB3);
  float lastVA = INFINITY, lastVB = INFINITY;
  int lastJA = -1, lastJB = -1;
  int myselA = 0, myselB = 0;
  for (int it = 0; it < K_; it++) {
    float gvA = tA0, gvB = tB0;
    int gjA = jA0, gjB = jB0;
#pragma unroll
    for (int off = 32; off; off >>= 1) {  // two independent butterflies, latencies overlap
      float v2A = __shfl_xor(gvA, off, 64);
      int i2A = __shfl_xor(gjA, off, 64);
      float v2B = __shfl_xor(gvB, off, 64);
      int i2B = __shfl_xor(gjB, off, 64);
      if (v2A > gvA || (v2A == gvA && i2A < gjA)) { gvA = v2A; gjA = i2A; }
      if (v2B > gvB || (v2B == gvB && i2B < gjB)) { gvB = v2B; gjB = i2B; }
    }
    if (lane == it) { myselA = gjA; myselB = gjB; }
    if (jA0 == gjA) {  // pop A's cache
      lastVA = tA0; lastJA = jA0;
      tA0 = tA1; jA0 = jA1;
      tA1 = tA2; jA1 = jA2;
      tA2 = tA3; jA2 = jA3;
      tA3 = -INFINITY; jA3 = 0x7FFFFFFF;
    }
    if (jB0 == gjB) {  // pop B's cache
      lastVB = tB0; lastJB = jB0;
      tB0 = tB1; jB0 = jB1;
      tB1 = tB2; jB1 = jB2;
      tB2 = tB3; jB2 = jB3;
      tB3 = -INFINITY; jB3 = 0x7FFFFFFF;
    }
    if (tA0 == -INFINITY && it < K_ - 1)
      tk_refill(vaA, lane, lastVA, lastJA, tA0, tA1, tA2, tA3, jA0, jA1, jA2, jA3);
    if (tB0 == -INFINITY && it < K_ - 1)
      tk_refill(vaB, lane, lastVB, lastJB, tB0, tB1, tB2, tB3, jB0, jB1, jB2, jB3);
  }
  if (lane < K_) {
    idx[((size_t)b * N_ + nA) * K_ + lane] = myselA;
    idx[((size_t)b * N_ + nB) * K_ + lane] = myselB;
  }
}

// ---- combine + fused next-layer rowsq ----
__global__ __launch_bounds__(384) void k_combine(const float* __restrict__ YZ,
                                                 const int* __restrict__ idx,
                                                 short* __restrict__ Hout,
                                                 short* __restrict__ Lout, int cofo,
                                                 float* __restrict__ sq) {
  __shared__ int sidx[4][K_];
  __shared__ float sred[384];
  int n0 = blockIdx.x * 4, b = blockIdx.y, t = threadIdx.x;
  if (t < 4 * K_) {
    int qq = t / K_, r = t % K_;
    sidx[qq][r] = idx[((size_t)b * N_ + n0 + qq) * K_ + r];
  }
  __syncthreads();
  int ro = t / 96, oc = (t % 96) * 4;
  int n = n0 + ro;
  const float* baseYZ = YZ + (size_t)b * N_ * (2 * C_);
  float4 z = *(const float4*)(baseYZ + (size_t)n * (2 * C_) + C_ + oc);
  float4 mx = make_float4(-INFINITY, -INFINITY, -INFINITY, -INFINITY);
#pragma unroll
  for (int k = 0; k < K_; k++) {
    float4 y = *(const float4*)(baseYZ + (size_t)sidx[ro][k] * (2 * C_) + oc);
    mx.x = fmaxf(mx.x, y.x + z.x);
    mx.y = fmaxf(mx.y, y.y + z.y);
    mx.z = fmaxf(mx.z, y.z + z.z);
    mx.w = fmaxf(mx.w, y.w + z.w);
  }
  float vv[4] = {mx.x, mx.y, mx.z, mx.w};
  short4v hs, ls;
  float ssum = 0.f;
#pragma unroll
  for (int j = 0; j < 4; j++) {
    float s = vv[j];
    s = s > 0.f ? s : SLOPE_ * s;  // leaky after max: identical (monotone)
    short hb = f2b(s);
    short lb = f2b(s - b2f(hb));
    hs[j] = hb;
    ls[j] = lb;
    float tv = b2f(hb) + b2f(lb);
    ssum += tv * tv;
  }
  size_t off = ((size_t)b * N_ + n) * (3 * C_) + cofo + oc;
  *(short4v*)(Hout + off) = hs;
  *(short4v*)(Lout + off) = ls;
  // fused rowsq for next layer (deterministic fixed-order reduce)
  sred[t] = ssum;
  __syncthreads();
  if (t < 4) {
    float s = 0.f;
    for (int u = 0; u < 96; u++) s += sred[t * 96 + u];
    sq[(size_t)b * N_ + n0 + t] = s;
  }
}

// ---- final partial GEMM (128x128 tiles, K-split x3): Pf[ks][b][n][o] raw fp32 ----
__global__ __launch_bounds__(256) void k_finpart(const short* __restrict__ Hcat,
                                                 const short* __restrict__ Lcat,
                                                 const short* __restrict__ WpH,
                                                 const short* __restrict__ WpL,
                                                 float* __restrict__ Pf) {
  __shared__ __align__(16) short sst[4][4096];
  int bi = blockIdx.x, bj = blockIdx.y;
  int b = blockIdx.z / 3, ks = blockIdx.z % 3;
  int K0 = ks * C_;
  int tid = threadIdx.x, lane = tid & 63, w = tid >> 6;
  int wr = w >> 1, wc = w & 1;
  int fr = lane & 15, r0 = (lane >> 4) << 2;
  const short* Hb = Hcat + (size_t)b * N_ * (3 * C_) + K0;
  const short* Lb = Lcat + (size_t)b * N_ * (3 * C_) + K0;
  floatx4 acc[4][4] = {};
  gemm128(Hb + (size_t)(bi * 128) * (3 * C_), Lb + (size_t)(bi * 128) * (3 * C_), 3 * C_,
          WpH + (size_t)(bj * 128) * (3 * C_) + K0, WpL + (size_t)(bj * 128) * (3 * C_) + K0,
          3 * C_, sst, tid, acc);
  float* Pb = Pf + ((size_t)ks * B_ + b) * N_ * C_;
  int rbase = bi * 128 + wr * 64;
  int cbase = bj * 128 + wc * 64;
#pragma unroll
  for (int n = 0; n < 4; n++) {
    int gcol = cbase + n * 16 + fr;
#pragma unroll
    for (int m = 0; m < 4; m++)
#pragma unroll
      for (int i = 0; i < 4; i++)
        Pb[(size_t)(rbase + m * 16 + r0 + i) * C_ + gcol] = acc[m][n][i];
  }
}

// ---- final reduce: sum 3 partials + bias, leaky, max over 16 rows, atomicMax ----
__global__ __launch_bounds__(384) void k_finred(const float* __restrict__ Pf,
                                                const float* __restrict__ bz2,
                                                unsigned* __restrict__ stage) {
  int nc = blockIdx.x, b = blockIdx.y, o = threadIdx.x;
  const size_t spl = (size_t)B_ * N_ * C_;
  float bzv = bz2[o];
  float vmax = -INFINITY;
  for (int nn = 0; nn < 16; nn++) {
    size_t base = ((size_t)b * N_ + nc * 16 + nn) * C_ + o;
    float y = Pf[base] + Pf[base + spl] + Pf[base + 2 * spl] + bzv;
    y = y > 0.f ? y : SLOPE_ * y;
    vmax = fmaxf(vmax, y);
  }
  atomicMax(stage + (size_t)b * C_ + o, fmap(vmax));
}

__global__ void k_unmap(const unsigned* __restrict__ stage, float* __restrict__ out) {
  int t = blockIdx.x * 256 + threadIdx.x;
  if (t < B_ * C_) out[t] = funmap(stage[t]);
}

// ---------------- host ----------------
extern "C" void kernel_launch(void* const* d_in, const int* in_sizes, int n_in,
                              void* d_out, int out_size, void* d_ws, size_t ws_size,
                              hipStream_t stream) {
  const float* x   = (const float*)d_in[0];
  const float* We[3] = {(const float*)d_in[2], (const float*)d_in[7], (const float*)d_in[12]};
  const float* g[3]  = {(const float*)d_in[3], (const float*)d_in[8], (const float*)d_in[13]};
  const float* bb[3] = {(const float*)d_in[4], (const float*)d_in[9], (const float*)d_in[14]};
  const float* m[3]  = {(const float*)d_in[5], (const float*)d_in[10], (const float*)d_in[15]};
  const float* v[3]  = {(const float*)d_in[6], (const float*)d_in[11], (const float*)d_in[16]};
  const float* Wp = (const float*)d_in[17];
  const float* gp = (const float*)d_in[18];
  const float* bp = (const float*)d_in[19];
  const float* mp = (const float*)d_in[20];
  const float* vp = (const float*)d_in[21];
  float* out = (float*)d_out;

  // workspace carve
  float* Gm = (float*)d_ws;                              // B*N*N f32; Pf aliases
  float* Pf = Gm;
  float* YZ = Gm + (size_t)B_ * N_ * N_;                 // B*N*2C
  float* sq = YZ + (size_t)B_ * N_ * 2 * C_;             // B*N
  int* idx = (int*)(sq + (size_t)B_ * N_);               // B*N*K
  short* Hcat = (short*)(idx + (size_t)B_ * N_ * K_);    // B*N*3C bf16
  short* Lcat = Hcat + (size_t)B_ * N_ * 3 * C_;         // B*N*3C bf16
  short* H0   = Lcat + (size_t)B_ * N_ * 3 * C_;         // B*N*C bf16
  short* L0   = H0 + (size_t)B_ * N_ * C_;               // B*N*C bf16
  short* WbfH = L0 + (size_t)B_ * N_ * C_;               // 3 x 2C*C
  short* WbfL = WbfH + (size_t)3 * 2 * C_ * C_;          // 3 x 2C*C
  short* WpH  = WbfL + (size_t)3 * 2 * C_ * C_;          // C*3C
  short* WpL  = WpH + (size_t)C_ * 3 * C_;               // C*3C
  float* bz   = (float*)(WpL + (size_t)C_ * 3 * C_);     // 3 x 2C
  float* bz2  = bz + 3 * 2 * C_;                         // C
  unsigned* stage = (unsigned*)(bz2 + C_);               // B*C

  // fused startup: weight preps (x4 vectorized) + stage init + transpose
  k_prep<<<dim3(1299 + 1536), 256, 0, stream>>>(
      x, We[0], g[0], bb[0], m[0], v[0], We[1], g[1], bb[1], m[1], v[1],
      We[2], g[2], bb[2], m[2], v[2], Wp, gp, bp, mp, vp,
      H0, L0, WbfH, WbfL, WpH, WpL, bz, bz2, stage);
  k_rowsq<<<dim3(B_ * N_ / 4), 256, 0, stream>>>(H0, L0, sq);

  for (int l = 0; l < 3; l++) {
    const short* Hin = (l == 0) ? H0 : Hcat;
    const short* Lin = (l == 0) ? L0 : Lcat;
    int ldh  = (l == 0) ? C_ : 3 * C_;
    int coff = (l == 0) ? 0 : (l - 1) * C_;

    // gram (272 blocks of 128x128) || yz (192 blocks) in one dispatch
    k_gramyz<<<dim3(136 * B_ + 16 * 6 * B_), 256, 0, stream>>>(
        Hin, Lin, ldh, coff, sq, Gm,
        WbfH + (size_t)l * 2 * C_ * C_, WbfL + (size_t)l * 2 * C_ * C_,
        bz + (size_t)l * 2 * C_, YZ);
    k_topk<<<dim3(N_ / 8, B_), 256, 0, stream>>>(Gm, idx);
    k_combine<<<dim3(N_ / 4, B_), 384, 0, stream>>>(YZ, idx, Hcat, Lcat, l * C_, sq);
  }

  // final projection: K-split partials (alias Gm) + fused reduce/max
  k_finpart<<<dim3(N_ / 128, C_ / 128, B_ * 3), 256, 0, stream>>>(Hcat, Lcat, WpH, WpL, Pf);
  k_finred<<<dim3(N_ / 16, B_), 384, 0, stream>>>(Pf, bz2, stage);
  k_unmap<<<dim3((B_ * C_ + 255) / 256), 256, 0, stream>>>(stage, out);
}

// Round 17
// 242.807 us; speedup vs baseline: 1.1228x; 1.1228x over previous
//
#include <hip/hip_runtime.h>
#include <hip/hip_bf16.h>
#include <cstdint>
#include <cstddef>

#define B_ 2
#define N_ 2048
#define C_ 384
#define K_ 20
#define EPS_ 1e-5f
#define SLOPE_ 0.2f

typedef __attribute__((ext_vector_type(8))) short short8;
typedef __attribute__((ext_vector_type(4))) short short4v;
typedef __attribute__((ext_vector_type(4))) float floatx4;

#define MFMA(a, b, c) __builtin_amdgcn_mfma_f32_16x16x32_bf16((a), (b), (c), 0, 0, 0)

// ---------------- helpers ----------------
__device__ __forceinline__ unsigned fmap(float f) {
  unsigned u = __float_as_uint(f);
  return (u & 0x80000000u) ? ~u : (u | 0x80000000u);
}
__device__ __forceinline__ float funmap(unsigned u) {
  unsigned bits = (u & 0x80000000u) ? (u ^ 0x80000000u) : ~u;
  return __uint_as_float(bits);
}
__device__ __forceinline__ short f2b(float f) {  // RNE fp32->bf16 bits
  __hip_bfloat16 h = __float2bfloat16(f);
  unsigned short u;
  __builtin_memcpy(&u, &h, 2);
  return (short)u;
}
__device__ __forceinline__ float b2f(short s) {
  unsigned u = ((unsigned)(unsigned short)s) << 16;
  return __uint_as_float(u);
}

// stage one 16x32 bf16 subtile in MFMA-fragment order (dest linear, src permuted)
__device__ __forceinline__ void stage16(const short* g, int ld, short* dst, int lane) {
  const short* src = g + (size_t)(lane & 15) * ld + ((lane >> 4) << 3);
  __builtin_amdgcn_global_load_lds(
      (const __attribute__((address_space(1))) void*)src,
      (__attribute__((address_space(3))) void*)dst, 16, 0, 0);
}

// ---- 128x128-tile, K=384, BK=32 split-bf16 GEMM core (m97 structure) ----
__device__ __forceinline__ void gemm128(const short* AH, const short* AL, int ldA,
                                        const short* BH, const short* BL, int ldB,
                                        short (*sst)[4096], int tid,
                                        floatx4 acc[4][4]) {
  int lane = tid & 63, w = tid >> 6;
  int wr = w >> 1, wc = w & 1;
  for (int kc = 0; kc < C_; kc += 32) {
    __syncthreads();
#pragma unroll
    for (int ss = 0; ss < 2; ss++) {
      int s = w * 2 + ss;  // subtile 0..7, rows s*16
      int ro = s * 16;
      stage16(AH + (size_t)ro * ldA + kc, ldA, &sst[0][s * 512], lane);
      stage16(AL + (size_t)ro * ldA + kc, ldA, &sst[1][s * 512], lane);
      stage16(BH + (size_t)ro * ldB + kc, ldB, &sst[2][s * 512], lane);
      stage16(BL + (size_t)ro * ldB + kc, ldB, &sst[3][s * 512], lane);
    }
    __syncthreads();
    short8 ah[4], al[4], bh[4], bl[4];
#pragma unroll
    for (int m = 0; m < 4; m++) {
      ah[m] = *(const short8*)&sst[0][(wr * 4 + m) * 512 + lane * 8];
      al[m] = *(const short8*)&sst[1][(wr * 4 + m) * 512 + lane * 8];
      bh[m] = *(const short8*)&sst[2][(wc * 4 + m) * 512 + lane * 8];
      bl[m] = *(const short8*)&sst[3][(wc * 4 + m) * 512 + lane * 8];
    }
#pragma unroll
    for (int m = 0; m < 4; m++)
#pragma unroll
      for (int n = 0; n < 4; n++) {
        acc[m][n] = MFMA(ah[m], bh[n], acc[m][n]);
        acc[m][n] = MFMA(ah[m], bl[n], acc[m][n]);
        acc[m][n] = MFMA(al[m], bh[n], acc[m][n]);
      }
  }
}

// ---- fused startup: 3x prepw (x4 vec), prepwp (x4 vec), stage-init, transpose ----
__global__ __launch_bounds__(256) void k_prep(
    const float* __restrict__ x,
    const float* __restrict__ We0, const float* __restrict__ g0, const float* __restrict__ b0,
    const float* __restrict__ m0, const float* __restrict__ v0,
    const float* __restrict__ We1, const float* __restrict__ g1, const float* __restrict__ b1,
    const float* __restrict__ m1, const float* __restrict__ v1,
    const float* __restrict__ We2, const float* __restrict__ g2, const float* __restrict__ b2,
    const float* __restrict__ m2, const float* __restrict__ v2,
    const float* __restrict__ Wp, const float* __restrict__ gp, const float* __restrict__ bp,
    const float* __restrict__ mp, const float* __restrict__ vp,
    short* __restrict__ H0, short* __restrict__ L0,
    short* __restrict__ WbfH, short* __restrict__ WbfL,
    short* __restrict__ WpH, short* __restrict__ WpL,
    float* __restrict__ bz, float* __restrict__ bz2,
    unsigned* __restrict__ stage) {
  __shared__ float tile[32][33];
  int bx = blockIdx.x;
  if (bx < 864) {  // edge weight prep, layer l, 4 elems/thread
    int l = bx / 288;
    int t4 = (bx % 288) * 256 + threadIdx.x;  // 73728 per layer (exact)
    const float* We = (l == 0) ? We0 : (l == 1) ? We1 : We2;
    const float* g  = (l == 0) ? g0  : (l == 1) ? g1  : g2;
    const float* bb = (l == 0) ? b0  : (l == 1) ? b1  : b2;
    const float* m  = (l == 0) ? m0  : (l == 1) ? m1  : m2;
    const float* v  = (l == 0) ? v0  : (l == 1) ? v1  : v2;
    short* WH = WbfH + (size_t)l * 2 * C_ * C_;
    short* WL = WbfL + (size_t)l * 2 * C_ * C_;
    float* bzl = bz + (size_t)l * 2 * C_;
    int o2 = t4 / (C_ / 4), c = (t4 % (C_ / 4)) * 4;
    int o = (o2 < C_) ? o2 : (o2 - C_);
    float sc = g[o] * rsqrtf(v[o] + EPS_);
    float4 wa = *(const float4*)(We + (size_t)o * 2 * C_ + c);
    float wv[4];
    if (o2 < C_) {
      wv[0] = sc * wa.x; wv[1] = sc * wa.y; wv[2] = sc * wa.z; wv[3] = sc * wa.w;
    } else {
      float4 wb = *(const float4*)(We + (size_t)o * 2 * C_ + C_ + c);
      wv[0] = sc * (wb.x - wa.x); wv[1] = sc * (wb.y - wa.y);
      wv[2] = sc * (wb.z - wa.z); wv[3] = sc * (wb.w - wa.w);
    }
    short4v hs, ls;
#pragma unroll
    for (int j = 0; j < 4; j++) {
      short hb = f2b(wv[j]);
      hs[j] = hb;
      ls[j] = f2b(wv[j] - b2f(hb));
    }
    *(short4v*)(WH + (size_t)t4 * 4) = hs;
    *(short4v*)(WL + (size_t)t4 * 4) = ls;
    if (t4 < 2 * C_ / 4) {
#pragma unroll
      for (int jj = 0; jj < 4; jj++) {
        int tt = t4 * 4 + jj;
        bzl[tt] = (tt < C_) ? 0.f
                            : (bb[tt - C_] - m[tt - C_] * (g[tt - C_] * rsqrtf(v[tt - C_] + EPS_)));
      }
    }
  } else if (bx < 1296) {  // final weight prep, 4 elems/thread
    int t4 = (bx - 864) * 256 + threadIdx.x;  // 110592 (exact)
    int o = t4 / (3 * C_ / 4);
    float sc = gp[o] * rsqrtf(vp[o] + EPS_);
    float4 wa = *(const float4*)(Wp + (size_t)t4 * 4);
    float wv[4] = {sc * wa.x, sc * wa.y, sc * wa.z, sc * wa.w};
    short4v hs, ls;
#pragma unroll
    for (int j = 0; j < 4; j++) {
      short hb = f2b(wv[j]);
      hs[j] = hb;
      ls[j] = f2b(wv[j] - b2f(hb));
    }
    *(short4v*)(WpH + (size_t)t4 * 4) = hs;
    *(short4v*)(WpL + (size_t)t4 * 4) = ls;
    if (t4 < C_ / 4) {
#pragma unroll
      for (int jj = 0; jj < 4; jj++) {
        int tt = t4 * 4 + jj;
        float s2 = gp[tt] * rsqrtf(vp[tt] + EPS_);
        bz2[tt] = bp[tt] - mp[tt] * s2;
      }
    }
  } else if (bx < 1299) {  // stage init
    int t = (bx - 1296) * 256 + threadIdx.x;
    if (t < B_ * C_) stage[t] = 0x007FFFFFu;  // fmap(-inf)
  } else {  // transpose x -> H0/L0
    int i = bx - 1299;
    int bn = i % 64, bc = (i / 64) % 12, b = i / 768;
    int tx = threadIdx.x & 31, ty = threadIdx.x >> 5;
    const float* src = x + ((size_t)b * C_ + bc * 32) * N_ + bn * 32;
#pragma unroll
    for (int j = 0; j < 32; j += 8)
      tile[ty + j][tx] = src[(size_t)(ty + j) * N_ + tx];
    __syncthreads();
#pragma unroll
    for (int j = 0; j < 32; j += 8) {
      float val = tile[tx][ty + j];
      short hb = f2b(val);
      short lb = f2b(val - b2f(hb));
      size_t off = ((size_t)b * N_ + bn * 32 + ty + j) * C_ + bc * 32 + tx;
      H0[off] = hb;
      L0[off] = lb;
    }
  }
}

// ---- row squared norms (layer 0 only) ----
__global__ __launch_bounds__(256) void k_rowsq(const short* __restrict__ H,
                                               const short* __restrict__ L,
                                               float* __restrict__ sq) {
  int row  = blockIdx.x * 4 + (threadIdx.x >> 6);
  int lane = threadIdx.x & 63;
  const short* ph = H + (size_t)row * C_;
  const short* pl = L + (size_t)row * C_;
  float v = 0.f;
  if (lane < C_ / 8) {
    short8 h8 = *(const short8*)(ph + lane * 8);
    short8 l8 = *(const short8*)(pl + lane * 8);
#pragma unroll
    for (int j = 0; j < 8; j++) {
      float t = b2f(h8[j]) + b2f(l8[j]);
      v += t * t;
    }
  }
#pragma unroll
  for (int off = 32; off; off >>= 1) v += __shfl_xor(v, off, 64);
  if (lane == 0) sq[row] = v;
}

// ---- mega kernel: gram (128x128 triangular, reg-mirror) || yz GEMM ----
__global__ __launch_bounds__(256) void k_gramyz(const short* __restrict__ H,
                                                const short* __restrict__ L,
                                                int ldh, int coff,
                                                const float* __restrict__ sq,
                                                float* __restrict__ Gm,
                                                const short* __restrict__ WH,
                                                const short* __restrict__ WL,
                                                const float* __restrict__ bz,
                                                float* __restrict__ YZ) {
  __shared__ __align__(16) short sst[4][4096];
  int bx = blockIdx.x;
  int tid = threadIdx.x, lane = tid & 63, w = tid >> 6;
  int wr = w >> 1, wc = w & 1;
  int fr = lane & 15, r0 = (lane >> 4) << 2;
  floatx4 acc[4][4] = {};

  if (bx < 136 * B_) {
    // ---------- gram path: 128x128 tiles, upper triangle ----------
    int b = bx / 136, t = bx % 136;
    int p = (int)((sqrtf(8.f * t + 1.f) - 1.f) * 0.5f);
    while ((p + 1) * (p + 2) / 2 <= t) p++;
    while (p * (p + 1) / 2 > t) p--;
    int q = t - p * (p + 1) / 2;
    int bi = q, bj = p;  // bi <= bj

    const short* Hb = H + (size_t)b * N_ * ldh + coff;
    const short* Lb = L + (size_t)b * N_ * ldh + coff;
    gemm128(Hb + (size_t)(bi * 128) * ldh, Lb + (size_t)(bi * 128) * ldh, ldh,
            Hb + (size_t)(bj * 128) * ldh, Lb + (size_t)(bj * 128) * ldh, ldh,
            sst, tid, acc);

    const float* sqb = sq + (size_t)b * N_;
    float* gbase = Gm + (size_t)b * N_ * N_;
    int rbase = bi * 128 + wr * 64;
    int cbase = bj * 128 + wc * 64;
#pragma unroll
    for (int n = 0; n < 4; n++) {
      int col = cbase + n * 16 + fr;
      float sqB = sqb[col];
#pragma unroll
      for (int m = 0; m < 4; m++)
#pragma unroll
        for (int i = 0; i < 4; i++)
          gbase[(size_t)(rbase + m * 16 + r0 + i) * N_ + col] = 2.f * acc[m][n][i] - sqB;
    }
    if (bi != bj) {
#pragma unroll
      for (int m = 0; m < 4; m++) {
        int mc0 = rbase + m * 16 + r0;
        float4 sqA = *(const float4*)(sqb + mc0);
        float sqs[4] = {sqA.x, sqA.y, sqA.z, sqA.w};
#pragma unroll
        for (int n = 0; n < 4; n++) {
          int mrow = cbase + n * 16 + fr;
          float4 mv = make_float4(2.f * acc[m][n][0] - sqs[0], 2.f * acc[m][n][1] - sqs[1],
                                  2.f * acc[m][n][2] - sqs[2], 2.f * acc[m][n][3] - sqs[3]);
          *(float4*)(gbase + (size_t)mrow * N_ + mc0) = mv;
        }
      }
    }
  } else {
    // ---------- yz path: 128x128 tiles ----------
    int i = bx - 136 * B_;
    int bi = i & 15, bj = (i >> 4) % 6, b = i / (16 * 6);
    const short* Hb = H + (size_t)b * N_ * ldh + coff;
    const short* Lb = L + (size_t)b * N_ * ldh + coff;
    gemm128(Hb + (size_t)(bi * 128) * ldh, Lb + (size_t)(bi * 128) * ldh, ldh,
            WH + (size_t)(bj * 128) * C_, WL + (size_t)(bj * 128) * C_, C_,
            sst, tid, acc);
    int rbase = bi * 128 + wr * 64;
    int cbase = bj * 128 + wc * 64;
#pragma unroll
    for (int n = 0; n < 4; n++) {
      int gcol = cbase + n * 16 + fr;
      float bzv = bz[gcol];
#pragma unroll
      for (int m = 0; m < 4; m++)
#pragma unroll
        for (int i2 = 0; i2 < 4; i2++)
          YZ[((size_t)b * N_ + rbase + m * 16 + r0 + i2) * (2 * C_) + gcol] =
              acc[m][n][i2] + bzv;
    }
  }
}

// ---- top-K: wave-per-row, per-lane sorted top-4 cache + lazy refill ----
__device__ __forceinline__ void tk_insert(float v, int j, bool valid,
                                          float& t0, float& t1, float& t2, float& t3,
                                          int& j0, int& j1, int& j2, int& j3) {
  bool c0 = valid && (v > t0);
  bool c1 = valid && (v > t1);
  bool c2 = valid && (v > t2);
  bool c3 = valid && (v > t3);
  t3 = c2 ? t2 : (c3 ? v : t3);  j3 = c2 ? j2 : (c3 ? j : j3);
  t2 = c1 ? t1 : (c2 ? v : t2);  j2 = c1 ? j1 : (c2 ? j : j2);
  t1 = c0 ? t0 : (c1 ? v : t1);  j1 = c0 ? j0 : (c1 ? j : j1);
  t0 = c0 ? v : t0;              j0 = c0 ? j : j0;
}

__device__ __forceinline__ void tk_refill(const float* va, int lane,
                                          float lastV, int lastJ,
                                          float& t0, float& t1, float& t2, float& t3,
                                          int& j0, int& j1, int& j2, int& j3) {
  t0 = t1 = t2 = t3 = -INFINITY;
  j0 = j1 = j2 = j3 = 0x7FFFFFFF;
#pragma unroll
  for (int s = 0; s < 32; s++) {
    int j = (s >> 2) * 256 + lane * 4 + (s & 3);
    float v = va[s];
    // strictly after (lastV, lastJ) in (v desc, j asc) order
    bool valid = (v < lastV) || (v == lastV && j > lastJ);
    tk_insert(v, j, valid, t0, t1, t2, t3, j0, j1, j2, j3);
  }
}

__global__ __launch_bounds__(256) void k_topk(const float* __restrict__ Gm,
                                              int* __restrict__ idx) {
  int lane = threadIdx.x & 63, wv = threadIdx.x >> 6;
  int n = blockIdx.x * 4 + wv, b = blockIdx.y;
  const float4* grow = (const float4*)(Gm + ((size_t)b * N_ + n) * N_);
  float va[32];
#pragma unroll
  for (int q = 0; q < 8; q++) {
    float4 t4 = grow[q * 64 + lane];
    va[q * 4 + 0] = t4.x; va[q * 4 + 1] = t4.y;
    va[q * 4 + 2] = t4.z; va[q * 4 + 3] = t4.w;
  }
  float t0, t1, t2, t3;
  int j0, j1, j2, j3;
  tk_refill(va, lane, INFINITY, -1, t0, t1, t2, t3, j0, j1, j2, j3);
  float lastV = INFINITY;
  int lastJ = -1;
  int mysel = 0;
  for (int it = 0; it < K_; it++) {
    float gv = t0;
    int gj = j0;
#pragma unroll
    for (int off = 32; off; off >>= 1) {
      float v2 = __shfl_xor(gv, off, 64);
      int i2 = __shfl_xor(gj, off, 64);
      if (v2 > gv || (v2 == gv && i2 < gj)) { gv = v2; gj = i2; }
    }
    if (lane == it) mysel = gj;
    if (j0 == gj) {  // this lane owned the winner: pop sorted cache
      lastV = t0; lastJ = j0;
      t0 = t1; j0 = j1;
      t1 = t2; j1 = j2;
      t2 = t3; j2 = j3;
      t3 = -INFINITY; j3 = 0x7FFFFFFF;
    }
    if (t0 == -INFINITY && it < K_ - 1)  // cache exhausted: refill past lastKey
      tk_refill(va, lane, lastV, lastJ, t0, t1, t2, t3, j0, j1, j2, j3);
  }
  if (lane < K_) idx[((size_t)b * N_ + n) * K_ + lane] = mysel;
}

// ---- combine + fused next-layer rowsq ----
__global__ __launch_bounds__(384) void k_combine(const float* __restrict__ YZ,
                                                 const int* __restrict__ idx,
                                                 short* __restrict__ Hout,
                                                 short* __restrict__ Lout, int cofo,
                                                 float* __restrict__ sq) {
  __shared__ int sidx[4][K_];
  __shared__ float sred[384];
  int n0 = blockIdx.x * 4, b = blockIdx.y, t = threadIdx.x;
  if (t < 4 * K_) {
    int qq = t / K_, r = t % K_;
    sidx[qq][r] = idx[((size_t)b * N_ + n0 + qq) * K_ + r];
  }
  __syncthreads();
  int ro = t / 96, oc = (t % 96) * 4;
  int n = n0 + ro;
  const float* baseYZ = YZ + (size_t)b * N_ * (2 * C_);
  float4 z = *(const float4*)(baseYZ + (size_t)n * (2 * C_) + C_ + oc);
  float4 mx = make_float4(-INFINITY, -INFINITY, -INFINITY, -INFINITY);
#pragma unroll
  for (int k = 0; k < K_; k++) {
    float4 y = *(const float4*)(baseYZ + (size_t)sidx[ro][k] * (2 * C_) + oc);
    mx.x = fmaxf(mx.x, y.x + z.x);
    mx.y = fmaxf(mx.y, y.y + z.y);
    mx.z = fmaxf(mx.z, y.z + z.z);
    mx.w = fmaxf(mx.w, y.w + z.w);
  }
  float vv[4] = {mx.x, mx.y, mx.z, mx.w};
  short4v hs, ls;
  float ssum = 0.f;
#pragma unroll
  for (int j = 0; j < 4; j++) {
    float s = vv[j];
    s = s > 0.f ? s : SLOPE_ * s;  // leaky after max: identical (monotone)
    short hb = f2b(s);
    short lb = f2b(s - b2f(hb));
    hs[j] = hb;
    ls[j] = lb;
    float tv = b2f(hb) + b2f(lb);
    ssum += tv * tv;
  }
  size_t off = ((size_t)b * N_ + n) * (3 * C_) + cofo + oc;
  *(short4v*)(Hout + off) = hs;
  *(short4v*)(Lout + off) = ls;
  // fused rowsq for next layer (deterministic fixed-order reduce)
  sred[t] = ssum;
  __syncthreads();
  if (t < 4) {
    float s = 0.f;
    for (int u = 0; u < 96; u++) s += sred[t * 96 + u];
    sq[(size_t)b * N_ + n0 + t] = s;
  }
}

// ---- final partial GEMM (128x128 tiles, K-split x3): Pf[ks][b][n][o] raw fp32 ----
__global__ __launch_bounds__(256) void k_finpart(const short* __restrict__ Hcat,
                                                 const short* __restrict__ Lcat,
                                                 const short* __restrict__ WpH,
                                                 const short* __restrict__ WpL,
                                                 float* __restrict__ Pf) {
  __shared__ __align__(16) short sst[4][4096];
  int bi = blockIdx.x, bj = blockIdx.y;
  int b = blockIdx.z / 3, ks = blockIdx.z % 3;
  int K0 = ks * C_;
  int tid = threadIdx.x, lane = tid & 63, w = tid >> 6;
  int wr = w >> 1, wc = w & 1;
  int fr = lane & 15, r0 = (lane >> 4) << 2;
  const short* Hb = Hcat + (size_t)b * N_ * (3 * C_) + K0;
  const short* Lb = Lcat + (size_t)b * N_ * (3 * C_) + K0;
  floatx4 acc[4][4] = {};
  gemm128(Hb + (size_t)(bi * 128) * (3 * C_), Lb + (size_t)(bi * 128) * (3 * C_), 3 * C_,
          WpH + (size_t)(bj * 128) * (3 * C_) + K0, WpL + (size_t)(bj * 128) * (3 * C_) + K0,
          3 * C_, sst, tid, acc);
  float* Pb = Pf + ((size_t)ks * B_ + b) * N_ * C_;
  int rbase = bi * 128 + wr * 64;
  int cbase = bj * 128 + wc * 64;
#pragma unroll
  for (int n = 0; n < 4; n++) {
    int gcol = cbase + n * 16 + fr;
#pragma unroll
    for (int m = 0; m < 4; m++)
#pragma unroll
      for (int i = 0; i < 4; i++)
        Pb[(size_t)(rbase + m * 16 + r0 + i) * C_ + gcol] = acc[m][n][i];
  }
}

// ---- final reduce: sum 3 partials + bias, leaky, max over 16 rows, atomicMax ----
__global__ __launch_bounds__(384) void k_finred(const float* __restrict__ Pf,
                                                const float* __restrict__ bz2,
                                                unsigned* __restrict__ stage) {
  int nc = blockIdx.x, b = blockIdx.y, o = threadIdx.x;
  const size_t spl = (size_t)B_ * N_ * C_;
  float bzv = bz2[o];
  float vmax = -INFINITY;
  for (int nn = 0; nn < 16; nn++) {
    size_t base = ((size_t)b * N_ + nc * 16 + nn) * C_ + o;
    float y = Pf[base] + Pf[base + spl] + Pf[base + 2 * spl] + bzv;
    y = y > 0.f ? y : SLOPE_ * y;
    vmax = fmaxf(vmax, y);
  }
  atomicMax(stage + (size_t)b * C_ + o, fmap(vmax));
}

__global__ void k_unmap(const unsigned* __restrict__ stage, float* __restrict__ out) {
  int t = blockIdx.x * 256 + threadIdx.x;
  if (t < B_ * C_) out[t] = funmap(stage[t]);
}

// ---------------- host ----------------
extern "C" void kernel_launch(void* const* d_in, const int* in_sizes, int n_in,
                              void* d_out, int out_size, void* d_ws, size_t ws_size,
                              hipStream_t stream) {
  const float* x   = (const float*)d_in[0];
  const float* We[3] = {(const float*)d_in[2], (const float*)d_in[7], (const float*)d_in[12]};
  const float* g[3]  = {(const float*)d_in[3], (const float*)d_in[8], (const float*)d_in[13]};
  const float* bb[3] = {(const float*)d_in[4], (const float*)d_in[9], (const float*)d_in[14]};
  const float* m[3]  = {(const float*)d_in[5], (const float*)d_in[10], (const float*)d_in[15]};
  const float* v[3]  = {(const float*)d_in[6], (const float*)d_in[11], (const float*)d_in[16]};
  const float* Wp = (const float*)d_in[17];
  const float* gp = (const float*)d_in[18];
  const float* bp = (const float*)d_in[19];
  const float* mp = (const float*)d_in[20];
  const float* vp = (const float*)d_in[21];
  float* out = (float*)d_out;

  // workspace carve
  float* Gm = (float*)d_ws;                              // B*N*N f32; Pf aliases
  float* Pf = Gm;
  float* YZ = Gm + (size_t)B_ * N_ * N_;                 // B*N*2C
  float* sq = YZ + (size_t)B_ * N_ * 2 * C_;             // B*N
  int* idx = (int*)(sq + (size_t)B_ * N_);               // B*N*K
  short* Hcat = (short*)(idx + (size_t)B_ * N_ * K_);    // B*N*3C bf16
  short* Lcat = Hcat + (size_t)B_ * N_ * 3 * C_;         // B*N*3C bf16
  short* H0   = Lcat + (size_t)B_ * N_ * 3 * C_;         // B*N*C bf16
  short* L0   = H0 + (size_t)B_ * N_ * C_;               // B*N*C bf16
  short* WbfH = L0 + (size_t)B_ * N_ * C_;               // 3 x 2C*C
  short* WbfL = WbfH + (size_t)3 * 2 * C_ * C_;          // 3 x 2C*C
  short* WpH  = WbfL + (size_t)3 * 2 * C_ * C_;          // C*3C
  short* WpL  = WpH + (size_t)C_ * 3 * C_;               // C*3C
  float* bz   = (float*)(WpL + (size_t)C_ * 3 * C_);     // 3 x 2C
  float* bz2  = bz + 3 * 2 * C_;                         // C
  unsigned* stage = (unsigned*)(bz2 + C_);               // B*C

  // fused startup: weight preps (x4 vectorized) + stage init + transpose
  k_prep<<<dim3(1299 + 1536), 256, 0, stream>>>(
      x, We[0], g[0], bb[0], m[0], v[0], We[1], g[1], bb[1], m[1], v[1],
      We[2], g[2], bb[2], m[2], v[2], Wp, gp, bp, mp, vp,
      H0, L0, WbfH, WbfL, WpH, WpL, bz, bz2, stage);
  k_rowsq<<<dim3(B_ * N_ / 4), 256, 0, stream>>>(H0, L0, sq);

  for (int l = 0; l < 3; l++) {
    const short* Hin = (l == 0) ? H0 : Hcat;
    const short* Lin = (l == 0) ? L0 : Lcat;
    int ldh  = (l == 0) ? C_ : 3 * C_;
    int coff = (l == 0) ? 0 : (l - 1) * C_;

    // gram (272 blocks of 128x128) || yz (192 blocks) in one dispatch
    k_gramyz<<<dim3(136 * B_ + 16 * 6 * B_), 256, 0, stream>>>(
        Hin, Lin, ldh, coff, sq, Gm,
        WbfH + (size_t)l * 2 * C_ * C_, WbfL + (size_t)l * 2 * C_ * C_,
        bz + (size_t)l * 2 * C_, YZ);
    k_topk<<<dim3(N_ / 4, B_), 256, 0, stream>>>(Gm, idx);
    k_combine<<<dim3(N_ / 4, B_), 384, 0, stream>>>(YZ, idx, Hcat, Lcat, l * C_, sq);
  }

  // final projection: K-split partials (alias Gm) + fused reduce/max
  k_finpart<<<dim3(N_ / 128, C_ / 128, B_ * 3), 256, 0, stream>>>(Hcat, Lcat, WpH, WpL, Pf);
  k_finred<<<dim3(N_ / 16, B_), 384, 0, stream>>>(Pf, bz2, stage);
  k_unmap<<<dim3((B_ * C_ + 255) / 256), 256, 0, stream>>>(stage, out);
}